// Round 6
// baseline (242.586 us; speedup 1.0000x reference)
//
#include <hip/hip_runtime.h>
#include <hip/hip_bf16.h>

#define NH 16
#define NKV 4
#define HD 128
// ATT_SCALE * log2(e): Q pre-scaled so P = exp2(S_mfma)
#define QSCALE 0.1275174272f

using bf16x8 = __attribute__((ext_vector_type(8))) __bf16;
using f32x4  = __attribute__((ext_vector_type(4))) float;
using u16x8  = __attribute__((ext_vector_type(8))) unsigned short;
using u16x2  = __attribute__((ext_vector_type(2))) unsigned short;

__device__ __forceinline__ unsigned short f2b(float f) {
  __hip_bfloat16 h = __float2bfloat16(f);
  return __builtin_bit_cast(unsigned short, h);
}
__device__ __forceinline__ float b2f(unsigned short u) {
  unsigned int v = ((unsigned int)u) << 16;
  return __builtin_bit_cast(float, v);
}

__device__ __forceinline__ void glds16(const unsigned short* g, unsigned short* l) {
  __builtin_amdgcn_global_load_lds(
      (const __attribute__((address_space(1))) unsigned int*)(const void*)g,
      (__attribute__((address_space(3))) unsigned int*)(void*)l, 16, 0, 0);
}

// ---------------- fused fp32 -> bf16 conversion (8 elems/thread) ----------
__global__ __launch_bounds__(256) void cvt_fused(const float* __restrict__ x,
                                                 const float* __restrict__ wq,
                                                 const float* __restrict__ wk,
                                                 const float* __restrict__ wv,
                                                 const float* __restrict__ wo,
                                                 unsigned short* __restrict__ xb,
                                                 unsigned short* __restrict__ wqkvb,
                                                 unsigned short* __restrict__ wob) {
  int i = blockIdx.x * 256 + threadIdx.x;
  const float* src;
  unsigned short* dst;
  int off;
  if (i < 1048576)      { src = x;  dst = xb;              off = i; }
  else if (i < 1572864) { src = wq; dst = wqkvb;           off = i - 1048576; }
  else if (i < 1703936) { src = wk; dst = wqkvb + 4194304; off = i - 1572864; }
  else if (i < 1835008) { src = wv; dst = wqkvb + 5242880; off = i - 1703936; }
  else                  { src = wo; dst = wob;             off = i - 1835008; }
  const float4* s4 = reinterpret_cast<const float4*>(src) + (size_t)off * 2;
  float4 v0 = s4[0], v1 = s4[1];
  u16x8 o;
  o[0] = f2b(v0.x); o[1] = f2b(v0.y); o[2] = f2b(v0.z); o[3] = f2b(v0.w);
  o[4] = f2b(v1.x); o[5] = f2b(v1.y); o[6] = f2b(v1.z); o[7] = f2b(v1.w);
  reinterpret_cast<u16x8*>(dst)[off] = o;
}

// ---------------- GEMM: C[M,N] = A[M,K] * B[N,K]^T ------------------------
// Tile 256x128, BK=32, 4 waves (2x2), wave = 128x64 (8x4 16x16x32 frags).
// A triple-buffered (stage lead 2), B double-buffered (lead 1).
// Counted vmcnt(4) boundary (A(t+2) stays in flight), raw s_barrier.
// LDS: 2 K-rows packed per 128B row, 16B-chunk XOR swizzle (cp = cl ^ (R&7)),
// inverse swizzle applied to global source (both-sides rule).
template<int CF32>
__global__ __launch_bounds__(256, 2) void gemm_big(const unsigned short* __restrict__ A,
                                                   const unsigned short* __restrict__ B,
                                                   void* __restrict__ C,
                                                   int N, int K) {
  __shared__ unsigned short As[3][8192];   // 256x32 per buf (16 KB)
  __shared__ unsigned short Bs[2][4096];   // 128x32 per buf (8 KB)  -> 64 KB total
  const int tid = threadIdx.x, lane = tid & 63, wid = tid >> 6;
  const int wm = wid >> 1, wn = wid & 1;
  const int row0 = blockIdx.y * 256, col0 = blockIdx.x * 128;
  const int fr = lane & 15, g = lane >> 4;
  const int NT = K >> 5;

  // stage source offsets (inverse-swizzled): chunk cid -> R=cid>>3, cp=cid&7,
  // cl = cp ^ (R&7), K-row = 2R + (cl>>2), k-chunk = cl&3
  size_t offA[4], offB[2];
#pragma unroll
  for (int l = 0; l < 4; l++) {
    int cid = tid + l * 256;
    int R = cid >> 3, cp = cid & 7;
    int cl = cp ^ (R & 7);
    offA[l] = (size_t)(row0 + 2 * R + (cl >> 2)) * K + (cl & 3) * 8;
  }
#pragma unroll
  for (int l = 0; l < 2; l++) {
    int cid = tid + l * 256;
    int R = cid >> 3, cp = cid & 7;
    int cl = cp ^ (R & 7);
    offB[l] = (size_t)(col0 + 2 * R + (cl >> 2)) * K + (cl & 3) * 8;
  }

  auto stageA = [&](int t, int sb) {
    int k0 = t * 32;
#pragma unroll
    for (int l = 0; l < 4; l++)
      glds16(A + offA[l] + k0, &As[sb][tid * 8 + l * 2048]);
  };
  auto stageB = [&](int t, int sb) {
    int k0 = t * 32;
#pragma unroll
    for (int l = 0; l < 2; l++)
      glds16(B + offB[l] + k0, &Bs[sb][tid * 8 + l * 2048]);
  };

  f32x4 acc[8][4];
#pragma unroll
  for (int i = 0; i < 8; i++)
#pragma unroll
    for (int j = 0; j < 4; j++) acc[i][j] = f32x4{0.f, 0.f, 0.f, 0.f};

  // prologue: A(0), B(0), A(1)  [order matters for vmcnt accounting]
  stageA(0, 0);
  stageB(0, 0);
  stageA(1, 1);
  asm volatile("s_waitcnt vmcnt(4)" ::: "memory");   // A(0)+B(0) landed; A(1) in flight
  __builtin_amdgcn_s_barrier();
  asm volatile("" ::: "memory");

  // read address component shared by A and B: physical chunk
  const int cp8 = ((((fr & 1) << 2) | g) ^ ((fr >> 1) & 7)) * 8;
  const int rrA = (fr >> 1);   // LDS-row lane component

  int rbA = 0, sbA = 2, rbB = 0;
#pragma unroll 1
  for (int t = 0; t < NT; ++t) {
    // issue-early staging (T14): B(t+1) then A(t+2)
    if (t + 1 < NT) stageB(t + 1, rbB ^ 1);
    if (t + 2 < NT) stageA(t + 2, sbA);

    bf16x8 af[8], bfr[4];
#pragma unroll
    for (int i = 0; i < 8; i++)
      af[i] = *reinterpret_cast<const bf16x8*>(&As[rbA][(wm * 64 + i * 8 + rrA) * 64 + cp8]);
#pragma unroll
    for (int j = 0; j < 4; j++)
      bfr[j] = *reinterpret_cast<const bf16x8*>(&Bs[rbB][(wn * 32 + j * 8 + rrA) * 64 + cp8]);

    __builtin_amdgcn_s_setprio(1);
#pragma unroll
    for (int i = 0; i < 8; i++)
#pragma unroll
      for (int j = 0; j < 4; j++)
        acc[i][j] = __builtin_amdgcn_mfma_f32_16x16x32_bf16(af[i], bfr[j], acc[i][j], 0, 0, 0);
    __builtin_amdgcn_s_setprio(0);

    if (t + 1 < NT) {
      if (t + 2 < NT) asm volatile("s_waitcnt vmcnt(4)" ::: "memory");  // leave A(t+2) in flight
      else            asm volatile("s_waitcnt vmcnt(0)" ::: "memory");  // final drain
      __builtin_amdgcn_s_barrier();
      asm volatile("" ::: "memory");
    }
    rbA = rbA == 2 ? 0 : rbA + 1;
    sbA = sbA == 2 ? 0 : sbA + 1;
    rbB ^= 1;
  }

  const int r4 = g * 4;
#pragma unroll
  for (int i = 0; i < 8; i++) {
#pragma unroll
    for (int j = 0; j < 4; j++) {
      int rb = row0 + wm * 128 + i * 16 + r4;
      int cb = col0 + wn * 64 + j * 16 + fr;
#pragma unroll
      for (int r = 0; r < 4; r++) {
        if (CF32)
          reinterpret_cast<float*>(C)[(size_t)(rb + r) * N + cb] = acc[i][j][r];
        else
          reinterpret_cast<unsigned short*>(C)[(size_t)(rb + r) * N + cb] = f2b(acc[i][j][r]);
      }
    }
  }
}

// ---------------- RoPE (reads fused qkv [4096][3072]) ---------------------
__global__ __launch_bounds__(256) void rope_kernel(const unsigned short* __restrict__ qkv,
                                                   const float* __restrict__ freqs,
                                                   unsigned short* __restrict__ qro,
                                                   unsigned short* __restrict__ kro,
                                                   float* __restrict__ newk) {
  const int NQ = 4096 * 16 * 64;
  const int NK = 4096 * 4 * 64;
  int idx = blockIdx.x * 256 + threadIdx.x;
  if (idx >= NQ + NK) return;
  if (idx < NQ) {
    int i = idx & 63;
    int h = (idx >> 6) & 15;
    int row = idx >> 10;             // b*2048 + s
    int s = row & 2047, b = row >> 11;
    float f = freqs[s * 64 + i];
    float c = cosf(f), sn = sinf(f);
    u16x2 xv = *reinterpret_cast<const u16x2*>(qkv + (size_t)row * 3072 + h * 128 + 2 * i);
    float x1 = b2f(xv.x), x2 = b2f(xv.y);
    float r1 = (x1 * c - x2 * sn) * QSCALE;
    float r2 = (x1 * sn + x2 * c) * QSCALE;
    u16x2 o; o.x = f2b(r1); o.y = f2b(r2);
    *reinterpret_cast<u16x2*>(qro + ((size_t)(b * 16 + h) * 2048 + s) * 128 + 2 * i) = o;
  } else {
    idx -= NQ;
    int i = idx & 63;
    int h = (idx >> 6) & 3;
    int row = idx >> 8;
    int s = row & 2047, b = row >> 11;
    float f = freqs[s * 64 + i];
    float c = cosf(f), sn = sinf(f);
    u16x2 xv = *reinterpret_cast<const u16x2*>(qkv + (size_t)row * 3072 + 2048 + h * 128 + 2 * i);
    float x1 = b2f(xv.x), x2 = b2f(xv.y);
    float r1 = x1 * c - x2 * sn;
    float r2 = x1 * sn + x2 * c;
    u16x2 o; o.x = f2b(r1); o.y = f2b(r2);
    *reinterpret_cast<u16x2*>(kro + ((size_t)(b * 4 + h) * 2048 + s) * 128 + 2 * i) = o;
    float2 of; of.x = r1; of.y = r2;
    *reinterpret_cast<float2*>(newk + (size_t)row * 512 + h * 128 + 2 * i) = of;
  }
}

// ---------------- V: LDS-tiled transpose -> vt[B][KVH][D][S] (slot-permuted)
__global__ __launch_bounds__(256) void vtrans_kernel(const unsigned short* __restrict__ qkv,
                                                     unsigned short* __restrict__ vt,
                                                     float* __restrict__ newv) {
  __shared__ unsigned short T[32][136];
  const int st = blockIdx.x;           // 0..63
  const int kvh = blockIdx.y & 3, b = blockIdx.y >> 2;
  const int s0 = st * 32;
  const int t = threadIdx.x;
  const int ls = t >> 3;               // local s 0..31
  const int ch = (t & 7) * 2;          // 16B-chunk pair
  const unsigned short* src = qkv + (size_t)(b * 2048 + s0 + ls) * 3072 + 2560 + kvh * 128 + ch * 8;
  u16x8 a0 = *reinterpret_cast<const u16x8*>(src);
  u16x8 a1 = *reinterpret_cast<const u16x8*>(src + 8);
  *reinterpret_cast<u16x8*>(&T[ls][ch * 8])     = a0;
  *reinterpret_cast<u16x8*>(&T[ls][ch * 8 + 8]) = a1;
  float* nv = newv + (size_t)(b * 2048 + s0 + ls) * 512 + kvh * 128 + ch * 8;
  float4 f0, f1, f2, f3;
  f0.x = b2f(a0[0]); f0.y = b2f(a0[1]); f0.z = b2f(a0[2]); f0.w = b2f(a0[3]);
  f1.x = b2f(a0[4]); f1.y = b2f(a0[5]); f1.z = b2f(a0[6]); f1.w = b2f(a0[7]);
  f2.x = b2f(a1[0]); f2.y = b2f(a1[1]); f2.z = b2f(a1[2]); f2.w = b2f(a1[3]);
  f3.x = b2f(a1[4]); f3.y = b2f(a1[5]); f3.z = b2f(a1[6]); f3.w = b2f(a1[7]);
  reinterpret_cast<float4*>(nv)[0] = f0;
  reinterpret_cast<float4*>(nv)[1] = f1;
  reinterpret_cast<float4*>(nv)[2] = f2;
  reinterpret_cast<float4*>(nv)[3] = f3;
  __syncthreads();
  const int d = t >> 1, half = t & 1;
  unsigned short* dst = vt + ((size_t)(b * 4 + kvh) * 128 + d) * 2048 + s0 + half * 16;
  u16x8 o0, o1;
#pragma unroll
  for (int q = 0; q < 8; q++) {
    int slot = half * 16 + q;
    int kl = ((slot >> 2) & 1) * 16 + (slot >> 3) * 4 + (slot & 3);
    o0[q] = T[kl][d];
  }
#pragma unroll
  for (int q = 0; q < 8; q++) {
    int slot = half * 16 + 8 + q;
    int kl = ((slot >> 2) & 1) * 16 + (slot >> 3) * 4 + (slot & 3);
    o1[q] = T[kl][d];
  }
  reinterpret_cast<u16x8*>(dst)[0] = o0;
  reinterpret_cast<u16x8*>(dst)[1] = o1;
}

// ---------------- flash attention: block = (q-tile16, kvh, b), 4 waves = 4 heads
__global__ __launch_bounds__(256, 4) void attn_kernel(const unsigned short* __restrict__ qro,
                                                      const unsigned short* __restrict__ kro,
                                                      const unsigned short* __restrict__ vt,
                                                      unsigned short* __restrict__ out) {
  __shared__ unsigned short Ks[2][32 * 128];   // [kv][d], rows 256B, swizzled
  __shared__ unsigned short Vs[2][64 * 64];    // paired-d rows 128B, swizzled
  const int tid = threadIdx.x, lane = tid & 63, w = tid >> 6;
  const int kvhb = blockIdx.x & 7;             // XCD pin: same (kvh,b) -> same XCD
  const int kvh = kvhb & 3, b = kvhb >> 2;
  const int t = 127 - (blockIdx.x >> 3);       // heavy-first
  const int h = kvh * 4 + w;                   // wave = one q-head
  const int qbase = t * 16;
  const int fr = lane & 15, g = lane >> 4, fk = g * 8;
  const unsigned short* Kp = kro + (size_t)(b * 4 + kvh) * 2048 * 128;
  const unsigned short* Vtp = vt + (size_t)(b * 4 + kvh) * 128 * 2048;
  const unsigned short* Qp = qro + ((size_t)(b * 16 + h) * 2048 + qbase) * 128;

  bf16x8 qf[4];
#pragma unroll
  for (int kk = 0; kk < 4; kk++)
    qf[kk] = *reinterpret_cast<const bf16x8*>(Qp + fr * 128 + kk * 32 + fk);

  u16x8 onesu;
#pragma unroll
  for (int j = 0; j < 8; j++) onesu[j] = 0x3F80;  // bf16 1.0
  bf16x8 ones = __builtin_bit_cast(bf16x8, onesu);

  f32x4 o[8];
#pragma unroll
  for (int dt = 0; dt < 8; dt++) o[dt] = f32x4{0.f, 0.f, 0.f, 0.f};
  f32x4 dacc = f32x4{0.f, 0.f, 0.f, 0.f};
  const int qrow_s = qbase + fr;
  const int nfull = (qbase >= 31) ? ((qbase - 31) >> 5) + 1 : 0;
  const int niter = nfull + 1;

  const int krow = w * 8 + (lane >> 4);        // K stage rows (+j*4)
  const int kcol = lane & 15;
  const int vrow = w * 16 + (lane >> 3);       // V stage rows, paired-d (+j*8)
  const int vcol = lane & 7;

  auto stage = [&](int kv0, int buf) {
    unsigned short* Kb = &Ks[buf][0];
    unsigned short* Vb = &Vs[buf][0];
#pragma unroll
    for (int j = 0; j < 2; j++) {
      int r = krow + j * 4;
      glds16(Kp + (size_t)(kv0 + r) * 128 + ((kcol ^ (r & 7)) * 8),
             Kb + (w * 8 + j * 4) * 128);
    }
#pragma unroll
    for (int j = 0; j < 2; j++) {
      int r = vrow + j * 8;
      int u = vcol ^ (r & 7);
      int d = 2 * r + (u >> 2);
      glds16(Vtp + (size_t)d * 2048 + kv0 + (u & 3) * 8,
             Vb + (w * 16 + j * 8) * 64);
    }
  };

  auto step = [&](int kv0, bool mask, int buf) {
    const unsigned short* Kb = &Ks[buf][0];
    const unsigned short* Vb = &Vs[buf][0];
    f32x4 sc[2];
    sc[0] = sc[1] = f32x4{0.f, 0.f, 0.f, 0.f};
    __builtin_amdgcn_s_setprio(1);
#pragma unroll
    for (int kk = 0; kk < 4; kk++) {
      int blk = ((kk * 4 + g) ^ (fr & 7)) * 8;
      bf16x8 ka0 = *reinterpret_cast<const bf16x8*>(Kb + (fr +  0) * 128 + blk);
      bf16x8 ka1 = *reinterpret_cast<const bf16x8*>(Kb + (fr + 16) * 128 + blk);
      sc[0] = __builtin_amdgcn_mfma_f32_16x16x32_bf16(ka0, qf[kk], sc[0], 0, 0, 0);
      sc[1] = __builtin_amdgcn_mfma_f32_16x16x32_bf16(ka1, qf[kk], sc[1], 0, 0, 0);
    }
    __builtin_amdgcn_s_setprio(0);
#pragma unroll
    for (int s = 0; s < 2; s++)
#pragma unroll
      for (int r = 0; r < 4; r++) {
        float v = sc[s][r];
        if (mask && (kv0 + 16 * s + 4 * g + r > qrow_s)) v = -1e30f;
        sc[s][r] = __builtin_amdgcn_exp2f(v);
      }
    u16x8 pau;
#pragma unroll
    for (int j = 0; j < 4; j++) {
      pau[j]     = f2b(sc[0][j]);
      pau[4 + j] = f2b(sc[1][j]);
    }
    bf16x8 pa = __builtin_bit_cast(bf16x8, pau);
    dacc = __builtin_amdgcn_mfma_f32_16x16x32_bf16(pa, ones, dacc, 0, 0, 0);
    __builtin_amdgcn_s_setprio(1);
#pragma unroll
    for (int dt = 0; dt < 8; dt++) {
      int jr = dt * 8 + (fr >> 1);
      int c = ((fr & 1) * 4 + g) ^ (fr >> 1);
      bf16x8 vf = *reinterpret_cast<const bf16x8*>(Vb + jr * 64 + c * 8);
      o[dt] = __builtin_amdgcn_mfma_f32_16x16x32_bf16(pa, vf, o[dt], 0, 0, 0);
    }
    __builtin_amdgcn_s_setprio(0);
  };

  stage(0, 0);
  int buf = 0;
  for (int i = 0; i < niter; i++) {
    __syncthreads();                 // tile i staged; prior reads of buf^1 done
    if (i + 1 < niter) stage((i + 1) * 32, buf ^ 1);
    step(i * 32, i == nfull, buf);
    buf ^= 1;
  }

#pragma unroll
  for (int r = 0; r < 4; r++) {
    float inv = 1.0f / dacc[r];
    int qrow = qbase + g * 4 + r;
    size_t rowoff = ((size_t)b * 2048 + qrow) * 2048 + (size_t)h * 128;
#pragma unroll
    for (int dt = 0; dt < 8; dt++)
      out[rowoff + dt * 16 + fr] = f2b(o[dt][r] * inv);
  }
}

// ---------------- launch ---------------------------------------------------
extern "C" void kernel_launch(void* const* d_in, const int* in_sizes, int n_in,
                              void* d_out, int out_size, void* d_ws, size_t ws_size,
                              hipStream_t stream) {
  const float* x  = (const float*)d_in[0];
  const float* wq = (const float*)d_in[1];
  const float* wk = (const float*)d_in[2];
  const float* wv = (const float*)d_in[3];
  const float* wo = (const float*)d_in[4];
  const float* freqs = (const float*)d_in[5];

  char* ws = (char*)d_ws;
  unsigned short* xb    = (unsigned short*)(ws);             // 16 MB, reused as attn out
  unsigned short* attn  = xb;
  unsigned short* wqkvb = (unsigned short*)(ws + 16777216);  // [3072][2048] bf16
  unsigned short* wob   = (unsigned short*)(ws + 29360128);
  unsigned short* qkv   = (unsigned short*)(ws + 37748736);  // [4096][3072] bf16
  unsigned short* qro   = (unsigned short*)(ws + 62914560);
  unsigned short* kro   = (unsigned short*)(ws + 79691776);
  unsigned short* vt    = (unsigned short*)(ws + 83886080);

  float* out_o = (float*)d_out;
  float* out_k = (float*)d_out + 8388608;
  float* out_v = (float*)d_out + 10485760;

  cvt_fused<<<9216, 256, 0, stream>>>(x, wq, wk, wv, wo, xb, wqkvb, wob);

  gemm_big<0><<<dim3(24, 16), 256, 0, stream>>>(xb, wqkvb, qkv, 3072, 2048);

  rope_kernel<<<20480, 256, 0, stream>>>(qkv, freqs, qro, kro, out_k);
  vtrans_kernel<<<dim3(64, 8), 256, 0, stream>>>(qkv, vt, out_v);

  attn_kernel<<<1024, 256, 0, stream>>>(qro, kro, vt, attn);

  gemm_big<1><<<dim3(16, 16), 256, 0, stream>>>(attn, wob, out_o, 2048, 2048);
}

// Round 7
// 216.453 us; speedup vs baseline: 1.1207x; 1.1207x over previous
//
#include <hip/hip_runtime.h>
#include <hip/hip_bf16.h>

#define NH 16
#define NKV 4
#define HD 128
// ATT_SCALE * log2(e): Q pre-scaled so P = exp2(S_mfma)
#define QSCALE 0.1275174272f

using bf16x8 = __attribute__((ext_vector_type(8))) __bf16;
using f32x4  = __attribute__((ext_vector_type(4))) float;
using u16x8  = __attribute__((ext_vector_type(8))) unsigned short;
using u16x2  = __attribute__((ext_vector_type(2))) unsigned short;

__device__ __forceinline__ unsigned short f2b(float f) {
  __hip_bfloat16 h = __float2bfloat16(f);
  return __builtin_bit_cast(unsigned short, h);
}
__device__ __forceinline__ float b2f(unsigned short u) {
  unsigned int v = ((unsigned int)u) << 16;
  return __builtin_bit_cast(float, v);
}

__device__ __forceinline__ void glds16(const unsigned short* g, unsigned short* l) {
  __builtin_amdgcn_global_load_lds(
      (const __attribute__((address_space(1))) unsigned int*)(const void*)g,
      (__attribute__((address_space(3))) unsigned int*)(void*)l, 16, 0, 0);
}

// ---------------- fused fp32 -> bf16 conversion (8 elems/thread) ----------
__global__ __launch_bounds__(256) void cvt_fused(const float* __restrict__ x,
                                                 const float* __restrict__ wq,
                                                 const float* __restrict__ wk,
                                                 const float* __restrict__ wv,
                                                 const float* __restrict__ wo,
                                                 unsigned short* __restrict__ xb,
                                                 unsigned short* __restrict__ wqkvb,
                                                 unsigned short* __restrict__ wob) {
  int i = blockIdx.x * 256 + threadIdx.x;
  const float* src;
  unsigned short* dst;
  int off;
  if (i < 1048576)      { src = x;  dst = xb;              off = i; }
  else if (i < 1572864) { src = wq; dst = wqkvb;           off = i - 1048576; }
  else if (i < 1703936) { src = wk; dst = wqkvb + 4194304; off = i - 1572864; }
  else if (i < 1835008) { src = wv; dst = wqkvb + 5242880; off = i - 1703936; }
  else                  { src = wo; dst = wob;             off = i - 1835008; }
  const float4* s4 = reinterpret_cast<const float4*>(src) + (size_t)off * 2;
  float4 v0 = s4[0], v1 = s4[1];
  u16x8 o;
  o[0] = f2b(v0.x); o[1] = f2b(v0.y); o[2] = f2b(v0.z); o[3] = f2b(v0.w);
  o[4] = f2b(v1.x); o[5] = f2b(v1.y); o[6] = f2b(v1.z); o[7] = f2b(v1.w);
  reinterpret_cast<u16x8*>(dst)[off] = o;
}

// ---------------- GEMM: C[M,N] = A[M,K] * B[N,K]^T ------------------------
// Tile (2*WROWS)x128, BK=32, 4 waves (2x2), wave = WROWSx64.
// BOTH A and B triple-buffered, staged 2 tiles ahead; boundary waits
// s_waitcnt vmcnt(L) (L = loads issued per tile) -> tile t+1 drained,
// tile t+2 stays in flight across the barrier (T3/T4).
// LDS: 2 K-rows packed per 128B row, 16B-chunk XOR swizzle (phys = cl^(R&7)),
// inverse swizzle on the global source (both-sides rule). 0 conflicts (R6).
template<int CF32, int WROWS>
__global__ __launch_bounds__(256, 2) void gemm_p(const unsigned short* __restrict__ A,
                                                 const unsigned short* __restrict__ B,
                                                 void* __restrict__ C,
                                                 int N, int K, int nbx) {
  constexpr int AF  = WROWS / 16;        // A frags per wave (8 or 4)
  constexpr int AL  = WROWS / 32;        // A loads/thread/tile (4 or 2)
  constexpr int ACH = WROWS * 8;         // A chunks per tile (1024 or 512)
  __shared__ unsigned short As[3][ACH * 8];
  __shared__ unsigned short Bs[3][4096];
  const int tid = threadIdx.x, lane = tid & 63, wid = tid >> 6;
  const int wm = wid >> 1, wn = wid & 1;
  // bijective XCD swizzle (gridDim.x % 8 == 0)
  const int cpx = gridDim.x >> 3;
  const int wgid = (blockIdx.x & 7) * cpx + (blockIdx.x >> 3);
  const int bx = wgid % nbx, by = wgid / nbx;
  const int row0 = by * (2 * WROWS), col0 = bx * 128;
  const int fr = lane & 15, g = lane >> 4;
  const int NT = K >> 5;

  size_t offA[AL], offB[2];
#pragma unroll
  for (int l = 0; l < AL; l++) {
    int cid = tid + l * 256;
    int R = cid >> 3, p = cid & 7, cl = p ^ (R & 7);
    offA[l] = (size_t)(row0 + 2 * R + (cl >> 2)) * K + (cl & 3) * 8;
  }
#pragma unroll
  for (int l = 0; l < 2; l++) {
    int cid = tid + l * 256;
    int R = cid >> 3, p = cid & 7, cl = p ^ (R & 7);
    offB[l] = (size_t)(col0 + 2 * R + (cl >> 2)) * K + (cl & 3) * 8;
  }

  auto stage = [&](int t, int sb) {
    int k0 = t * 32;
#pragma unroll
    for (int l = 0; l < AL; l++)
      glds16(A + offA[l] + k0, &As[sb][tid * 8 + l * 2048]);
#pragma unroll
    for (int l = 0; l < 2; l++)
      glds16(B + offB[l] + k0, &Bs[sb][tid * 8 + l * 2048]);
  };

  f32x4 acc[AF][4];
#pragma unroll
  for (int i = 0; i < AF; i++)
#pragma unroll
    for (int j = 0; j < 4; j++) acc[i][j] = f32x4{0.f, 0.f, 0.f, 0.f};

  // prologue: tiles 0 and 1
  stage(0, 0);
  stage(1, 1);
  if constexpr (WROWS == 128)
    asm volatile("s_waitcnt vmcnt(6)" ::: "memory");   // tile0 landed, tile1 in flight
  else
    asm volatile("s_waitcnt vmcnt(4)" ::: "memory");
  __builtin_amdgcn_s_barrier();
  asm volatile("" ::: "memory");

  const int cp8 = ((((fr & 1) << 2) | g) ^ ((fr >> 1) & 7)) * 8;
  const int rr = fr >> 1;

  int rb = 0, sb = 2;
#pragma unroll 1
  for (int t = 0; t < NT; ++t) {
    if (t + 2 < NT) stage(t + 2, sb);

    bf16x8 af[AF], bfr[4];
#pragma unroll
    for (int i = 0; i < AF; i++)
      af[i] = *reinterpret_cast<const bf16x8*>(&As[rb][(wm * (WROWS / 2) + i * 8 + rr) * 64 + cp8]);
#pragma unroll
    for (int j = 0; j < 4; j++)
      bfr[j] = *reinterpret_cast<const bf16x8*>(&Bs[rb][(wn * 32 + j * 8 + rr) * 64 + cp8]);

    __builtin_amdgcn_s_setprio(1);
#pragma unroll
    for (int i = 0; i < AF; i++)
#pragma unroll
      for (int j = 0; j < 4; j++)
        acc[i][j] = __builtin_amdgcn_mfma_f32_16x16x32_bf16(af[i], bfr[j], acc[i][j], 0, 0, 0);
    __builtin_amdgcn_s_setprio(0);

    if (t + 1 < NT) {
      if (t + 2 < NT) {
        if constexpr (WROWS == 128)
          asm volatile("s_waitcnt vmcnt(6)" ::: "memory");  // drain t+1, keep t+2 in flight
        else
          asm volatile("s_waitcnt vmcnt(4)" ::: "memory");
      } else {
        asm volatile("s_waitcnt vmcnt(0)" ::: "memory");    // tail drain
      }
      __builtin_amdgcn_s_barrier();
      asm volatile("" ::: "memory");
    }
    rb = rb == 2 ? 0 : rb + 1;
    sb = sb == 2 ? 0 : sb + 1;
  }

  const int r4 = g * 4;
#pragma unroll
  for (int i = 0; i < AF; i++) {
#pragma unroll
    for (int j = 0; j < 4; j++) {
      int rbase = row0 + wm * WROWS + i * 16 + r4;
      int cb = col0 + wn * 64 + j * 16 + fr;
#pragma unroll
      for (int r = 0; r < 4; r++) {
        if (CF32)
          reinterpret_cast<float*>(C)[(size_t)(rbase + r) * N + cb] = acc[i][j][r];
        else
          reinterpret_cast<unsigned short*>(C)[(size_t)(rbase + r) * N + cb] = f2b(acc[i][j][r]);
      }
    }
  }
}

// ---------------- RoPE (reads fused qkv [4096][3072]) ---------------------
__global__ __launch_bounds__(256) void rope_kernel(const unsigned short* __restrict__ qkv,
                                                   const float* __restrict__ freqs,
                                                   unsigned short* __restrict__ qro,
                                                   unsigned short* __restrict__ kro,
                                                   float* __restrict__ newk) {
  const int NQ = 4096 * 16 * 64;
  const int NK = 4096 * 4 * 64;
  int idx = blockIdx.x * 256 + threadIdx.x;
  if (idx >= NQ + NK) return;
  if (idx < NQ) {
    int i = idx & 63;
    int h = (idx >> 6) & 15;
    int row = idx >> 10;             // b*2048 + s
    int s = row & 2047, b = row >> 11;
    float f = freqs[s * 64 + i];
    float c = cosf(f), sn = sinf(f);
    u16x2 xv = *reinterpret_cast<const u16x2*>(qkv + (size_t)row * 3072 + h * 128 + 2 * i);
    float x1 = b2f(xv.x), x2 = b2f(xv.y);
    float r1 = (x1 * c - x2 * sn) * QSCALE;
    float r2 = (x1 * sn + x2 * c) * QSCALE;
    u16x2 o; o.x = f2b(r1); o.y = f2b(r2);
    *reinterpret_cast<u16x2*>(qro + ((size_t)(b * 16 + h) * 2048 + s) * 128 + 2 * i) = o;
  } else {
    idx -= NQ;
    int i = idx & 63;
    int h = (idx >> 6) & 3;
    int row = idx >> 8;
    int s = row & 2047, b = row >> 11;
    float f = freqs[s * 64 + i];
    float c = cosf(f), sn = sinf(f);
    u16x2 xv = *reinterpret_cast<const u16x2*>(qkv + (size_t)row * 3072 + 2048 + h * 128 + 2 * i);
    float x1 = b2f(xv.x), x2 = b2f(xv.y);
    float r1 = x1 * c - x2 * sn;
    float r2 = x1 * sn + x2 * c;
    u16x2 o; o.x = f2b(r1); o.y = f2b(r2);
    *reinterpret_cast<u16x2*>(kro + ((size_t)(b * 4 + h) * 2048 + s) * 128 + 2 * i) = o;
    float2 of; of.x = r1; of.y = r2;
    *reinterpret_cast<float2*>(newk + (size_t)row * 512 + h * 128 + 2 * i) = of;
  }
}

// ---------------- V: LDS-tiled transpose -> vt[B][KVH][D][S] (slot-permuted)
__global__ __launch_bounds__(256) void vtrans_kernel(const unsigned short* __restrict__ qkv,
                                                     unsigned short* __restrict__ vt,
                                                     float* __restrict__ newv) {
  __shared__ unsigned short T[32][136];
  const int st = blockIdx.x;           // 0..63
  const int kvh = blockIdx.y & 3, b = blockIdx.y >> 2;
  const int s0 = st * 32;
  const int t = threadIdx.x;
  const int ls = t >> 3;               // local s 0..31
  const int ch = (t & 7) * 2;          // 16B-chunk pair
  const unsigned short* src = qkv + (size_t)(b * 2048 + s0 + ls) * 3072 + 2560 + kvh * 128 + ch * 8;
  u16x8 a0 = *reinterpret_cast<const u16x8*>(src);
  u16x8 a1 = *reinterpret_cast<const u16x8*>(src + 8);
  *reinterpret_cast<u16x8*>(&T[ls][ch * 8])     = a0;
  *reinterpret_cast<u16x8*>(&T[ls][ch * 8 + 8]) = a1;
  float* nv = newv + (size_t)(b * 2048 + s0 + ls) * 512 + kvh * 128 + ch * 8;
  float4 f0, f1, f2, f3;
  f0.x = b2f(a0[0]); f0.y = b2f(a0[1]); f0.z = b2f(a0[2]); f0.w = b2f(a0[3]);
  f1.x = b2f(a0[4]); f1.y = b2f(a0[5]); f1.z = b2f(a0[6]); f1.w = b2f(a0[7]);
  f2.x = b2f(a1[0]); f2.y = b2f(a1[1]); f2.z = b2f(a1[2]); f2.w = b2f(a1[3]);
  f3.x = b2f(a1[4]); f3.y = b2f(a1[5]); f3.z = b2f(a1[6]); f3.w = b2f(a1[7]);
  reinterpret_cast<float4*>(nv)[0] = f0;
  reinterpret_cast<float4*>(nv)[1] = f1;
  reinterpret_cast<float4*>(nv)[2] = f2;
  reinterpret_cast<float4*>(nv)[3] = f3;
  __syncthreads();
  const int d = t >> 1, half = t & 1;
  unsigned short* dst = vt + ((size_t)(b * 4 + kvh) * 128 + d) * 2048 + s0 + half * 16;
  u16x8 o0, o1;
#pragma unroll
  for (int q = 0; q < 8; q++) {
    int slot = half * 16 + q;
    int kl = ((slot >> 2) & 1) * 16 + (slot >> 3) * 4 + (slot & 3);
    o0[q] = T[kl][d];
  }
#pragma unroll
  for (int q = 0; q < 8; q++) {
    int slot = half * 16 + 8 + q;
    int kl = ((slot >> 2) & 1) * 16 + (slot >> 3) * 4 + (slot & 3);
    o1[q] = T[kl][d];
  }
  reinterpret_cast<u16x8*>(dst)[0] = o0;
  reinterpret_cast<u16x8*>(dst)[1] = o1;
}

// ---------------- flash attention: block = (q-tile16, kvh, b), 4 waves = 4 heads
__global__ __launch_bounds__(256, 4) void attn_kernel(const unsigned short* __restrict__ qro,
                                                      const unsigned short* __restrict__ kro,
                                                      const unsigned short* __restrict__ vt,
                                                      unsigned short* __restrict__ out) {
  __shared__ unsigned short Ks[2][32 * 128];   // [kv][d], rows 256B, swizzled
  __shared__ unsigned short Vs[2][64 * 64];    // paired-d rows 128B, swizzled
  const int tid = threadIdx.x, lane = tid & 63, w = tid >> 6;
  const int kvhb = blockIdx.x & 7;             // XCD pin: same (kvh,b) -> same XCD
  const int kvh = kvhb & 3, b = kvhb >> 2;
  const int t = 127 - (blockIdx.x >> 3);       // heavy-first
  const int h = kvh * 4 + w;                   // wave = one q-head
  const int qbase = t * 16;
  const int fr = lane & 15, g = lane >> 4, fk = g * 8;
  const unsigned short* Kp = kro + (size_t)(b * 4 + kvh) * 2048 * 128;
  const unsigned short* Vtp = vt + (size_t)(b * 4 + kvh) * 128 * 2048;
  const unsigned short* Qp = qro + ((size_t)(b * 16 + h) * 2048 + qbase) * 128;

  bf16x8 qf[4];
#pragma unroll
  for (int kk = 0; kk < 4; kk++)
    qf[kk] = *reinterpret_cast<const bf16x8*>(Qp + fr * 128 + kk * 32 + fk);

  u16x8 onesu;
#pragma unroll
  for (int j = 0; j < 8; j++) onesu[j] = 0x3F80;  // bf16 1.0
  bf16x8 ones = __builtin_bit_cast(bf16x8, onesu);

  f32x4 o[8];
#pragma unroll
  for (int dt = 0; dt < 8; dt++) o[dt] = f32x4{0.f, 0.f, 0.f, 0.f};
  f32x4 dacc = f32x4{0.f, 0.f, 0.f, 0.f};
  const int qrow_s = qbase + fr;
  const int nfull = (qbase >= 31) ? ((qbase - 31) >> 5) + 1 : 0;
  const int niter = nfull + 1;

  const int krow = w * 8 + (lane >> 4);        // K stage rows (+j*4)
  const int kcol = lane & 15;
  const int vrow = w * 16 + (lane >> 3);       // V stage rows, paired-d (+j*8)
  const int vcol = lane & 7;

  auto stage = [&](int kv0, int buf) {
    unsigned short* Kb = &Ks[buf][0];
    unsigned short* Vb = &Vs[buf][0];
#pragma unroll
    for (int j = 0; j < 2; j++) {
      int r = krow + j * 4;
      glds16(Kp + (size_t)(kv0 + r) * 128 + ((kcol ^ (r & 7)) * 8),
             Kb + (w * 8 + j * 4) * 128);
    }
#pragma unroll
    for (int j = 0; j < 2; j++) {
      int r = vrow + j * 8;
      int u = vcol ^ (r & 7);
      int d = 2 * r + (u >> 2);
      glds16(Vtp + (size_t)d * 2048 + kv0 + (u & 3) * 8,
             Vb + (w * 16 + j * 8) * 64);
    }
  };

  auto step = [&](int kv0, bool mask, int buf) {
    const unsigned short* Kb = &Ks[buf][0];
    const unsigned short* Vb = &Vs[buf][0];
    f32x4 sc[2];
    sc[0] = sc[1] = f32x4{0.f, 0.f, 0.f, 0.f};
    __builtin_amdgcn_s_setprio(1);
#pragma unroll
    for (int kk = 0; kk < 4; kk++) {
      int blk = ((kk * 4 + g) ^ (fr & 7)) * 8;
      bf16x8 ka0 = *reinterpret_cast<const bf16x8*>(Kb + (fr +  0) * 128 + blk);
      bf16x8 ka1 = *reinterpret_cast<const bf16x8*>(Kb + (fr + 16) * 128 + blk);
      sc[0] = __builtin_amdgcn_mfma_f32_16x16x32_bf16(ka0, qf[kk], sc[0], 0, 0, 0);
      sc[1] = __builtin_amdgcn_mfma_f32_16x16x32_bf16(ka1, qf[kk], sc[1], 0, 0, 0);
    }
    __builtin_amdgcn_s_setprio(0);
#pragma unroll
    for (int s = 0; s < 2; s++)
#pragma unroll
      for (int r = 0; r < 4; r++) {
        float v = sc[s][r];
        if (mask && (kv0 + 16 * s + 4 * g + r > qrow_s)) v = -1e30f;
        sc[s][r] = __builtin_amdgcn_exp2f(v);
      }
    u16x8 pau;
#pragma unroll
    for (int j = 0; j < 4; j++) {
      pau[j]     = f2b(sc[0][j]);
      pau[4 + j] = f2b(sc[1][j]);
    }
    bf16x8 pa = __builtin_bit_cast(bf16x8, pau);
    dacc = __builtin_amdgcn_mfma_f32_16x16x32_bf16(pa, ones, dacc, 0, 0, 0);
    __builtin_amdgcn_s_setprio(1);
#pragma unroll
    for (int dt = 0; dt < 8; dt++) {
      int jr = dt * 8 + (fr >> 1);
      int c = ((fr & 1) * 4 + g) ^ (fr >> 1);
      bf16x8 vf = *reinterpret_cast<const bf16x8*>(Vb + jr * 64 + c * 8);
      o[dt] = __builtin_amdgcn_mfma_f32_16x16x32_bf16(pa, vf, o[dt], 0, 0, 0);
    }
    __builtin_amdgcn_s_setprio(0);
  };

  stage(0, 0);
  int buf = 0;
  for (int i = 0; i < niter; i++) {
    __syncthreads();                 // tile i staged; prior reads of buf^1 done
    if (i + 1 < niter) stage((i + 1) * 32, buf ^ 1);
    step(i * 32, i == nfull, buf);
    buf ^= 1;
  }

#pragma unroll
  for (int r = 0; r < 4; r++) {
    float inv = 1.0f / dacc[r];
    int qrow = qbase + g * 4 + r;
    size_t rowoff = ((size_t)b * 2048 + qrow) * 2048 + (size_t)h * 128;
#pragma unroll
    for (int dt = 0; dt < 8; dt++)
      out[rowoff + dt * 16 + fr] = f2b(o[dt][r] * inv);
  }
}

// ---------------- launch ---------------------------------------------------
extern "C" void kernel_launch(void* const* d_in, const int* in_sizes, int n_in,
                              void* d_out, int out_size, void* d_ws, size_t ws_size,
                              hipStream_t stream) {
  const float* x  = (const float*)d_in[0];
  const float* wq = (const float*)d_in[1];
  const float* wk = (const float*)d_in[2];
  const float* wv = (const float*)d_in[3];
  const float* wo = (const float*)d_in[4];
  const float* freqs = (const float*)d_in[5];

  char* ws = (char*)d_ws;
  unsigned short* xb    = (unsigned short*)(ws);             // 16 MB, reused as attn out
  unsigned short* attn  = xb;
  unsigned short* wqkvb = (unsigned short*)(ws + 16777216);  // [3072][2048] bf16
  unsigned short* wob   = (unsigned short*)(ws + 29360128);
  unsigned short* qkv   = (unsigned short*)(ws + 37748736);  // [4096][3072] bf16
  unsigned short* qro   = (unsigned short*)(ws + 62914560);
  unsigned short* kro   = (unsigned short*)(ws + 79691776);
  unsigned short* vt    = (unsigned short*)(ws + 83886080);

  float* out_o = (float*)d_out;
  float* out_k = (float*)d_out + 8388608;
  float* out_v = (float*)d_out + 10485760;

  cvt_fused<<<9216, 256, 0, stream>>>(x, wq, wk, wv, wo, xb, wqkvb, wob);

  // QKV: M=4096 (BM=256 -> 16), N=3072 (BN=128 -> 24): 384 blocks
  gemm_p<0, 128><<<384, 256, 0, stream>>>(xb, wqkvb, qkv, 3072, 2048, 24);

  rope_kernel<<<20480, 256, 0, stream>>>(qkv, freqs, qro, kro, out_k);
  vtrans_kernel<<<dim3(64, 8), 256, 0, stream>>>(qkv, vt, out_v);

  attn_kernel<<<1024, 256, 0, stream>>>(qro, kro, vt, attn);

  // O: M=4096 (BM=128 -> 32), N=2048 (BN=128 -> 16): 512 blocks, 2/CU
  gemm_p<1, 64><<<512, 256, 0, stream>>>(attn, wob, out_o, 2048, 2048, 16);
}

// Round 8
// 212.147 us; speedup vs baseline: 1.1435x; 1.0203x over previous
//
#include <hip/hip_runtime.h>
#include <hip/hip_bf16.h>

#define NH 16
#define NKV 4
#define HD 128
// ATT_SCALE * log2(e): Q pre-scaled so P = exp2(S_mfma)
#define QSCALE 0.1275174272f

using bf16x8 = __attribute__((ext_vector_type(8))) __bf16;
using f32x4  = __attribute__((ext_vector_type(4))) float;
using u16x8  = __attribute__((ext_vector_type(8))) unsigned short;
using u16x2  = __attribute__((ext_vector_type(2))) unsigned short;

__device__ __forceinline__ unsigned short f2b(float f) {
  __hip_bfloat16 h = __float2bfloat16(f);
  return __builtin_bit_cast(unsigned short, h);
}
__device__ __forceinline__ float b2f(unsigned short u) {
  unsigned int v = ((unsigned int)u) << 16;
  return __builtin_bit_cast(float, v);
}

__device__ __forceinline__ void glds16(const unsigned short* g, unsigned short* l) {
  __builtin_amdgcn_global_load_lds(
      (const __attribute__((address_space(1))) unsigned int*)(const void*)g,
      (__attribute__((address_space(3))) unsigned int*)(void*)l, 16, 0, 0);
}

// ---------------- fused fp32 -> bf16 conversion (8 elems/thread) ----------
__global__ __launch_bounds__(256) void cvt_fused(const float* __restrict__ x,
                                                 const float* __restrict__ wq,
                                                 const float* __restrict__ wk,
                                                 const float* __restrict__ wv,
                                                 const float* __restrict__ wo,
                                                 unsigned short* __restrict__ xb,
                                                 unsigned short* __restrict__ wqkvb,
                                                 unsigned short* __restrict__ wob) {
  int i = blockIdx.x * 256 + threadIdx.x;
  const float* src;
  unsigned short* dst;
  int off;
  if (i < 1048576)      { src = x;  dst = xb;              off = i; }
  else if (i < 1572864) { src = wq; dst = wqkvb;           off = i - 1048576; }
  else if (i < 1703936) { src = wk; dst = wqkvb + 4194304; off = i - 1572864; }
  else if (i < 1835008) { src = wv; dst = wqkvb + 5242880; off = i - 1703936; }
  else                  { src = wo; dst = wob;             off = i - 1835008; }
  const float4* s4 = reinterpret_cast<const float4*>(src) + (size_t)off * 2;
  float4 v0 = s4[0], v1 = s4[1];
  u16x8 o;
  o[0] = f2b(v0.x); o[1] = f2b(v0.y); o[2] = f2b(v0.z); o[3] = f2b(v0.w);
  o[4] = f2b(v1.x); o[5] = f2b(v1.y); o[6] = f2b(v1.z); o[7] = f2b(v1.w);
  reinterpret_cast<u16x8*>(dst)[off] = o;
}

// ---------------- GEMM, 8-phase-style schedule (T3+T4+T5+T2) --------------
// C[M,N] = A[M,K]*B[N,K]^T. Tile BM=128 x BN=256, BK=64. 512 thr, 8 waves
// (2M x 4N), wave = 64x64 (4x4 frags). LDS: 3 rotating K-tile buffers
// (A 16KB, B 32KB each -> 144KB): stage(t+2) targets a buffer with NO live
// reader (reader was tile t-1, finished) -> WAR-free by construction.
// Per K-tile, 2 phases (M-half quadrants): {ds_read subtile | stage half |
// barrier | lgkmcnt(0) | 16 MFMA | barrier}; K-tile boundary adds vmcnt(6)
// (tile t+2's 6 loads stay in flight; waited tile staged a full tile ago).
// LDS swizzle: row r, 16B-chunk phys = chunk ^ (r&7); inverse on glds source.
template<int CF32>
__global__ __launch_bounds__(512, 1) void gemm8(const unsigned short* __restrict__ A,
                                                const unsigned short* __restrict__ B,
                                                void* __restrict__ C,
                                                int N, int K, int nbx) {
  __shared__ unsigned short As[3][128 * 64];
  __shared__ unsigned short Bs[3][256 * 64];
  const int tid = threadIdx.x, lane = tid & 63;
  const int wid = tid >> 6, wm = wid >> 2, wn = wid & 3;
  const int cpx = gridDim.x >> 3;                 // bijective XCD swizzle (grid%8==0)
  const int wgid = (blockIdx.x & 7) * cpx + (blockIdx.x >> 3);
  const int bx = wgid % nbx, by = wgid / nbx;
  const int row0 = by * 128, col0 = bx * 256;
  const int fr = lane & 15, g = lane >> 4;
  const int NT = K >> 6;

  // stage source offsets (inverse-swizzled)
  size_t offA[2], offB[4];
#pragma unroll
  for (int l = 0; l < 2; l++) {
    int cid = tid + l * 512, R = cid >> 3, phys = cid & 7, cl = phys ^ (R & 7);
    offA[l] = (size_t)(row0 + R) * K + cl * 8;
  }
#pragma unroll
  for (int l = 0; l < 4; l++) {
    int cid = tid + l * 512, R = cid >> 3, phys = cid & 7, cl = phys ^ (R & 7);
    offB[l] = (size_t)(col0 + R) * K + cl * 8;
  }

  auto stage0 = [&](int t, int sb) {   // 3 loads: A half + B first quarter
    int k0 = t * 64;
    glds16(A + offA[0] + k0, &As[sb][tid * 8]);
    glds16(A + offA[1] + k0, &As[sb][(tid + 512) * 8]);
    glds16(B + offB[0] + k0, &Bs[sb][tid * 8]);
  };
  auto stage1 = [&](int t, int sb) {   // 3 loads: B rest
    int k0 = t * 64;
    glds16(B + offB[1] + k0, &Bs[sb][(tid + 512) * 8]);
    glds16(B + offB[2] + k0, &Bs[sb][(tid + 1024) * 8]);
    glds16(B + offB[3] + k0, &Bs[sb][(tid + 1536) * 8]);
  };

  const int ca = fr & 7;
  auto ldA = [&](int rb, int mf, int ks) {
    return *reinterpret_cast<const bf16x8*>(
        &As[rb][(wm * 64 + mf * 16 + fr) * 64 + (((ks << 2) | g) ^ ca) * 8]);
  };
  auto ldB = [&](int rb, int nf, int ks) {
    return *reinterpret_cast<const bf16x8*>(
        &Bs[rb][(wn * 64 + nf * 16 + fr) * 64 + (((ks << 2) | g) ^ ca) * 8]);
  };

  f32x4 acc[4][4];
#pragma unroll
  for (int i = 0; i < 4; i++)
#pragma unroll
    for (int j = 0; j < 4; j++) acc[i][j] = f32x4{0.f, 0.f, 0.f, 0.f};

  // prologue: tiles 0,1 staged; tile 0 landed (6 of tile 1 stay in flight)
  stage0(0, 0); stage1(0, 0);
  stage0(1, 1); stage1(1, 1);
  asm volatile("s_waitcnt vmcnt(6)" ::: "memory");
  __builtin_amdgcn_s_barrier();
  __builtin_amdgcn_sched_barrier(0);

  int rb = 0, sb = 2;
#pragma unroll 1
  for (int t = 0; t < NT; ++t) {
    // ---- phase A: B all frags + A M-half 0; stage half 0 of tile t+2 ----
    bf16x8 bfr[4][2];
#pragma unroll
    for (int nf = 0; nf < 4; nf++) { bfr[nf][0] = ldB(rb, nf, 0); bfr[nf][1] = ldB(rb, nf, 1); }
    bf16x8 a0[2][2];
#pragma unroll
    for (int mf = 0; mf < 2; mf++) { a0[mf][0] = ldA(rb, mf, 0); a0[mf][1] = ldA(rb, mf, 1); }
    if (t + 2 < NT) stage0(t + 2, sb);
    __builtin_amdgcn_s_barrier();
    asm volatile("s_waitcnt lgkmcnt(0)" ::: "memory");
    __builtin_amdgcn_sched_barrier(0);
    __builtin_amdgcn_s_setprio(1);
#pragma unroll
    for (int mf = 0; mf < 2; mf++)
#pragma unroll
      for (int nf = 0; nf < 4; nf++) {
        acc[mf][nf] = __builtin_amdgcn_mfma_f32_16x16x32_bf16(a0[mf][0], bfr[nf][0], acc[mf][nf], 0, 0, 0);
        acc[mf][nf] = __builtin_amdgcn_mfma_f32_16x16x32_bf16(a0[mf][1], bfr[nf][1], acc[mf][nf], 0, 0, 0);
      }
    __builtin_amdgcn_s_setprio(0);
    __builtin_amdgcn_sched_barrier(0);
    __builtin_amdgcn_s_barrier();

    // ---- phase B: A M-half 1; stage half 1 of tile t+2 ----
    bf16x8 a1[2][2];
#pragma unroll
    for (int mf = 0; mf < 2; mf++) { a1[mf][0] = ldA(rb, mf + 2, 0); a1[mf][1] = ldA(rb, mf + 2, 1); }
    if (t + 2 < NT) stage1(t + 2, sb);
    __builtin_amdgcn_s_barrier();
    asm volatile("s_waitcnt lgkmcnt(0)" ::: "memory");
    __builtin_amdgcn_sched_barrier(0);
    __builtin_amdgcn_s_setprio(1);
#pragma unroll
    for (int mf = 0; mf < 2; mf++)
#pragma unroll
      for (int nf = 0; nf < 4; nf++) {
        acc[mf + 2][nf] = __builtin_amdgcn_mfma_f32_16x16x32_bf16(a1[mf][0], bfr[nf][0], acc[mf + 2][nf], 0, 0, 0);
        acc[mf + 2][nf] = __builtin_amdgcn_mfma_f32_16x16x32_bf16(a1[mf][1], bfr[nf][1], acc[mf + 2][nf], 0, 0, 0);
      }
    __builtin_amdgcn_s_setprio(0);
    __builtin_amdgcn_sched_barrier(0);

    // ---- K-tile boundary: drain tile t+1, keep t+2 in flight ----
    if (t + 1 < NT) {
      if (t + 2 < NT) asm volatile("s_waitcnt vmcnt(6)" ::: "memory");
      else            asm volatile("s_waitcnt vmcnt(0)" ::: "memory");
      __builtin_amdgcn_s_barrier();
      __builtin_amdgcn_sched_barrier(0);
    }
    rb = rb == 2 ? 0 : rb + 1;
    sb = sb == 2 ? 0 : sb + 1;
  }

  // epilogue
#pragma unroll
  for (int i = 0; i < 4; i++) {
#pragma unroll
    for (int j = 0; j < 4; j++) {
      int rbase = row0 + wm * 64 + i * 16 + g * 4;
      int cb = col0 + wn * 64 + j * 16 + fr;
#pragma unroll
      for (int r = 0; r < 4; r++) {
        if (CF32)
          reinterpret_cast<float*>(C)[(size_t)(rbase + r) * N + cb] = acc[i][j][r];
        else
          reinterpret_cast<unsigned short*>(C)[(size_t)(rbase + r) * N + cb] = f2b(acc[i][j][r]);
      }
    }
  }
}

// ---------------- RoPE (reads fused qkv [4096][3072]) ---------------------
__global__ __launch_bounds__(256) void rope_kernel(const unsigned short* __restrict__ qkv,
                                                   const float* __restrict__ freqs,
                                                   unsigned short* __restrict__ qro,
                                                   unsigned short* __restrict__ kro,
                                                   float* __restrict__ newk) {
  const int NQ = 4096 * 16 * 64;
  const int NK = 4096 * 4 * 64;
  int idx = blockIdx.x * 256 + threadIdx.x;
  if (idx >= NQ + NK) return;
  if (idx < NQ) {
    int i = idx & 63;
    int h = (idx >> 6) & 15;
    int row = idx >> 10;             // b*2048 + s
    int s = row & 2047, b = row >> 11;
    float f = freqs[s * 64 + i];
    float c = cosf(f), sn = sinf(f);
    u16x2 xv = *reinterpret_cast<const u16x2*>(qkv + (size_t)row * 3072 + h * 128 + 2 * i);
    float x1 = b2f(xv.x), x2 = b2f(xv.y);
    float r1 = (x1 * c - x2 * sn) * QSCALE;
    float r2 = (x1 * sn + x2 * c) * QSCALE;
    u16x2 o; o.x = f2b(r1); o.y = f2b(r2);
    *reinterpret_cast<u16x2*>(qro + ((size_t)(b * 16 + h) * 2048 + s) * 128 + 2 * i) = o;
  } else {
    idx -= NQ;
    int i = idx & 63;
    int h = (idx >> 6) & 3;
    int row = idx >> 8;
    int s = row & 2047, b = row >> 11;
    float f = freqs[s * 64 + i];
    float c = cosf(f), sn = sinf(f);
    u16x2 xv = *reinterpret_cast<const u16x2*>(qkv + (size_t)row * 3072 + 2048 + h * 128 + 2 * i);
    float x1 = b2f(xv.x), x2 = b2f(xv.y);
    float r1 = x1 * c - x2 * sn;
    float r2 = x1 * sn + x2 * c;
    u16x2 o; o.x = f2b(r1); o.y = f2b(r2);
    *reinterpret_cast<u16x2*>(kro + ((size_t)(b * 4 + h) * 2048 + s) * 128 + 2 * i) = o;
    float2 of; of.x = r1; of.y = r2;
    *reinterpret_cast<float2*>(newk + (size_t)row * 512 + h * 128 + 2 * i) = of;
  }
}

// ---------------- V: LDS-tiled transpose -> vt[B][KVH][D][S] (slot-permuted)
__global__ __launch_bounds__(256) void vtrans_kernel(const unsigned short* __restrict__ qkv,
                                                     unsigned short* __restrict__ vt,
                                                     float* __restrict__ newv) {
  __shared__ unsigned short T[32][136];
  const int st = blockIdx.x;           // 0..63
  const int kvh = blockIdx.y & 3, b = blockIdx.y >> 2;
  const int s0 = st * 32;
  const int t = threadIdx.x;
  const int ls = t >> 3;               // local s 0..31
  const int ch = (t & 7) * 2;          // 16B-chunk pair
  const unsigned short* src = qkv + (size_t)(b * 2048 + s0 + ls) * 3072 + 2560 + kvh * 128 + ch * 8;
  u16x8 a0 = *reinterpret_cast<const u16x8*>(src);
  u16x8 a1 = *reinterpret_cast<const u16x8*>(src + 8);
  *reinterpret_cast<u16x8*>(&T[ls][ch * 8])     = a0;
  *reinterpret_cast<u16x8*>(&T[ls][ch * 8 + 8]) = a1;
  float* nv = newv + (size_t)(b * 2048 + s0 + ls) * 512 + kvh * 128 + ch * 8;
  float4 f0, f1, f2, f3;
  f0.x = b2f(a0[0]); f0.y = b2f(a0[1]); f0.z = b2f(a0[2]); f0.w = b2f(a0[3]);
  f1.x = b2f(a0[4]); f1.y = b2f(a0[5]); f1.z = b2f(a0[6]); f1.w = b2f(a0[7]);
  f2.x = b2f(a1[0]); f2.y = b2f(a1[1]); f2.z = b2f(a1[2]); f2.w = b2f(a1[3]);
  f3.x = b2f(a1[4]); f3.y = b2f(a1[5]); f3.z = b2f(a1[6]); f3.w = b2f(a1[7]);
  reinterpret_cast<float4*>(nv)[0] = f0;
  reinterpret_cast<float4*>(nv)[1] = f1;
  reinterpret_cast<float4*>(nv)[2] = f2;
  reinterpret_cast<float4*>(nv)[3] = f3;
  __syncthreads();
  const int d = t >> 1, half = t & 1;
  unsigned short* dst = vt + ((size_t)(b * 4 + kvh) * 128 + d) * 2048 + s0 + half * 16;
  u16x8 o0, o1;
#pragma unroll
  for (int q = 0; q < 8; q++) {
    int slot = half * 16 + q;
    int kl = ((slot >> 2) & 1) * 16 + (slot >> 3) * 4 + (slot & 3);
    o0[q] = T[kl][d];
  }
#pragma unroll
  for (int q = 0; q < 8; q++) {
    int slot = half * 16 + 8 + q;
    int kl = ((slot >> 2) & 1) * 16 + (slot >> 3) * 4 + (slot & 3);
    o1[q] = T[kl][d];
  }
  reinterpret_cast<u16x8*>(dst)[0] = o0;
  reinterpret_cast<u16x8*>(dst)[1] = o1;
}

// ---------------- flash attention: block = (q-tile16, kvh, b), 4 waves = 4 heads
__global__ __launch_bounds__(256, 4) void attn_kernel(const unsigned short* __restrict__ qro,
                                                      const unsigned short* __restrict__ kro,
                                                      const unsigned short* __restrict__ vt,
                                                      unsigned short* __restrict__ out) {
  __shared__ unsigned short Ks[2][32 * 128];   // [kv][d], rows 256B, swizzled
  __shared__ unsigned short Vs[2][64 * 64];    // paired-d rows 128B, swizzled
  const int tid = threadIdx.x, lane = tid & 63, w = tid >> 6;
  const int kvhb = blockIdx.x & 7;             // XCD pin: same (kvh,b) -> same XCD
  const int kvh = kvhb & 3, b = kvhb >> 2;
  const int t = 127 - (blockIdx.x >> 3);       // heavy-first
  const int h = kvh * 4 + w;                   // wave = one q-head
  const int qbase = t * 16;
  const int fr = lane & 15, g = lane >> 4, fk = g * 8;
  const unsigned short* Kp = kro + (size_t)(b * 4 + kvh) * 2048 * 128;
  const unsigned short* Vtp = vt + (size_t)(b * 4 + kvh) * 128 * 2048;
  const unsigned short* Qp = qro + ((size_t)(b * 16 + h) * 2048 + qbase) * 128;

  bf16x8 qf[4];
#pragma unroll
  for (int kk = 0; kk < 4; kk++)
    qf[kk] = *reinterpret_cast<const bf16x8*>(Qp + fr * 128 + kk * 32 + fk);

  u16x8 onesu;
#pragma unroll
  for (int j = 0; j < 8; j++) onesu[j] = 0x3F80;  // bf16 1.0
  bf16x8 ones = __builtin_bit_cast(bf16x8, onesu);

  f32x4 o[8];
#pragma unroll
  for (int dt = 0; dt < 8; dt++) o[dt] = f32x4{0.f, 0.f, 0.f, 0.f};
  f32x4 dacc = f32x4{0.f, 0.f, 0.f, 0.f};
  const int qrow_s = qbase + fr;
  const int nfull = (qbase >= 31) ? ((qbase - 31) >> 5) + 1 : 0;
  const int niter = nfull + 1;

  const int krow = w * 8 + (lane >> 4);        // K stage rows (+j*4)
  const int kcol = lane & 15;
  const int vrow = w * 16 + (lane >> 3);       // V stage rows, paired-d (+j*8)
  const int vcol = lane & 7;

  auto stage = [&](int kv0, int buf) {
    unsigned short* Kb = &Ks[buf][0];
    unsigned short* Vb = &Vs[buf][0];
#pragma unroll
    for (int j = 0; j < 2; j++) {
      int r = krow + j * 4;
      glds16(Kp + (size_t)(kv0 + r) * 128 + ((kcol ^ (r & 7)) * 8),
             Kb + (w * 8 + j * 4) * 128);
    }
#pragma unroll
    for (int j = 0; j < 2; j++) {
      int r = vrow + j * 8;
      int u = vcol ^ (r & 7);
      int d = 2 * r + (u >> 2);
      glds16(Vtp + (size_t)d * 2048 + kv0 + (u & 3) * 8,
             Vb + (w * 16 + j * 8) * 64);
    }
  };

  auto step = [&](int kv0, bool mask, int buf) {
    const unsigned short* Kb = &Ks[buf][0];
    const unsigned short* Vb = &Vs[buf][0];
    f32x4 sc[2];
    sc[0] = sc[1] = f32x4{0.f, 0.f, 0.f, 0.f};
    __builtin_amdgcn_s_setprio(1);
#pragma unroll
    for (int kk = 0; kk < 4; kk++) {
      int blk = ((kk * 4 + g) ^ (fr & 7)) * 8;
      bf16x8 ka0 = *reinterpret_cast<const bf16x8*>(Kb + (fr +  0) * 128 + blk);
      bf16x8 ka1 = *reinterpret_cast<const bf16x8*>(Kb + (fr + 16) * 128 + blk);
      sc[0] = __builtin_amdgcn_mfma_f32_16x16x32_bf16(ka0, qf[kk], sc[0], 0, 0, 0);
      sc[1] = __builtin_amdgcn_mfma_f32_16x16x32_bf16(ka1, qf[kk], sc[1], 0, 0, 0);
    }
    __builtin_amdgcn_s_setprio(0);
#pragma unroll
    for (int s = 0; s < 2; s++)
#pragma unroll
      for (int r = 0; r < 4; r++) {
        float v = sc[s][r];
        if (mask && (kv0 + 16 * s + 4 * g + r > qrow_s)) v = -1e30f;
        sc[s][r] = __builtin_amdgcn_exp2f(v);
      }
    u16x8 pau;
#pragma unroll
    for (int j = 0; j < 4; j++) {
      pau[j]     = f2b(sc[0][j]);
      pau[4 + j] = f2b(sc[1][j]);
    }
    bf16x8 pa = __builtin_bit_cast(bf16x8, pau);
    dacc = __builtin_amdgcn_mfma_f32_16x16x32_bf16(pa, ones, dacc, 0, 0, 0);
    __builtin_amdgcn_s_setprio(1);
#pragma unroll
    for (int dt = 0; dt < 8; dt++) {
      int jr = dt * 8 + (fr >> 1);
      int c = ((fr & 1) * 4 + g) ^ (fr >> 1);
      bf16x8 vf = *reinterpret_cast<const bf16x8*>(Vb + jr * 64 + c * 8);
      o[dt] = __builtin_amdgcn_mfma_f32_16x16x32_bf16(pa, vf, o[dt], 0, 0, 0);
    }
    __builtin_amdgcn_s_setprio(0);
  };

  stage(0, 0);
  int buf = 0;
  for (int i = 0; i < niter; i++) {
    __syncthreads();                 // tile i staged; prior reads of buf^1 done
    if (i + 1 < niter) stage((i + 1) * 32, buf ^ 1);
    step(i * 32, i == nfull, buf);
    buf ^= 1;
  }

#pragma unroll
  for (int r = 0; r < 4; r++) {
    float inv = 1.0f / dacc[r];
    int qrow = qbase + g * 4 + r;
    size_t rowoff = ((size_t)b * 2048 + qrow) * 2048 + (size_t)h * 128;
#pragma unroll
    for (int dt = 0; dt < 8; dt++)
      out[rowoff + dt * 16 + fr] = f2b(o[dt][r] * inv);
  }
}

// ---------------- launch ---------------------------------------------------
extern "C" void kernel_launch(void* const* d_in, const int* in_sizes, int n_in,
                              void* d_out, int out_size, void* d_ws, size_t ws_size,
                              hipStream_t stream) {
  const float* x  = (const float*)d_in[0];
  const float* wq = (const float*)d_in[1];
  const float* wk = (const float*)d_in[2];
  const float* wv = (const float*)d_in[3];
  const float* wo = (const float*)d_in[4];
  const float* freqs = (const float*)d_in[5];

  char* ws = (char*)d_ws;
  unsigned short* xb    = (unsigned short*)(ws);             // 16 MB, reused as attn out
  unsigned short* attn  = xb;
  unsigned short* wqkvb = (unsigned short*)(ws + 16777216);  // [3072][2048] bf16
  unsigned short* wob   = (unsigned short*)(ws + 29360128);
  unsigned short* qkv   = (unsigned short*)(ws + 37748736);  // [4096][3072] bf16
  unsigned short* qro   = (unsigned short*)(ws + 62914560);
  unsigned short* kro   = (unsigned short*)(ws + 79691776);
  unsigned short* vt    = (unsigned short*)(ws + 83886080);

  float* out_o = (float*)d_out;
  float* out_k = (float*)d_out + 8388608;
  float* out_v = (float*)d_out + 10485760;

  cvt_fused<<<9216, 256, 0, stream>>>(x, wq, wk, wv, wo, xb, wqkvb, wob);

  // QKV: M=4096 (BM=128 -> 32) x N=3072 (BN=256 -> 12) = 384 blocks
  gemm8<0><<<384, 512, 0, stream>>>(xb, wqkvb, qkv, 3072, 2048, 12);

  rope_kernel<<<20480, 256, 0, stream>>>(qkv, freqs, qro, kro, out_k);
  vtrans_kernel<<<dim3(64, 8), 256, 0, stream>>>(qkv, vt, out_v);

  attn_kernel<<<1024, 256, 0, stream>>>(qro, kro, vt, attn);

  // O: M=4096 (32) x N=2048 (BN=256 -> 8) = 256 blocks = 1/CU exactly
  gemm8<1><<<256, 512, 0, stream>>>(attn, wob, out_o, 2048, 2048, 8);
}